// Round 5
// baseline (462.137 us; speedup 1.0000x reference)
//
#include <hip/hip_runtime.h>

// Problem constants
#define BB 8
#define NN 512
#define TT 64
#define SS 65      // T+1
#define DD 256
#define HH 256
#define G4 1024    // 4*H

__device__ __forceinline__ float fsigmoid(float x) {
    return __builtin_amdgcn_rcpf(1.f + __expf(-x));
}
__device__ __forceinline__ float ftanh(float x) {
    float e = __expf(2.f * x);
    return fmaf(-2.f, __builtin_amdgcn_rcpf(e + 1.f), 1.f);
}

// ---------------------------------------------------------------------------
// pre_kernel: blocks [0,144): xg0 = seq @ w_ih[0]^T + b_ih0 + b_hh0  (seq synth)
//             blocks [144,400): dual-feat GEMM (attn_feat, hop_feat)
//             blocks [400,1456): S0/S1 (h,tag) slot init  (replay-safe)
// ---------------------------------------------------------------------------
__global__ void __launch_bounds__(256) pre_kernel(
    const float* __restrict__ lstm_in, const float* __restrict__ init_i,
    const float* __restrict__ init_h, const float* __restrict__ w_ih,
    const float* __restrict__ b_ih, const float* __restrict__ b_hh,
    float* __restrict__ xg0,
    const float* __restrict__ attn_mem, const float* __restrict__ attn_wm,
    const float* __restrict__ hop_wm,
    float* __restrict__ attn_feat, float* __restrict__ hop_feat,
    unsigned long long* __restrict__ S0, unsigned long long* __restrict__ S1)
{
    const int tid = threadIdx.x;
    const int blk = blockIdx.x;
    if (blk >= 400) {
        int i = (blk - 400) * 256 + tid;   // [0, 270336)
        if (i < 2048) {
            S0[i] = (1ULL << 32) | (unsigned long long)(unsigned)__float_as_uint(init_h[i & 255]);
        } else if (i < 4096) {
            S1[i - 2048] = (1ULL << 32)
                         | (unsigned long long)(unsigned)__float_as_uint(init_h[HH + (i & 255)]);
        } else if (i < 4096 + 65 * 2048) {
            S0[2048 + (i - 4096)] = 0ULL;
        } else if (i < 4096 + 130 * 2048) {
            S1[2048 + (i - (4096 + 65 * 2048))] = 0ULL;
        }
        return;
    }
    __shared__ __align__(16) float smem[3264];
    const int tm = (tid >> 4) * 4, tn = (tid & 15) * 4;
    const int arow = tid >> 2, akq = (tid & 3) << 2;

    if (blk < 144) {
        // ---- xg0 GEMM: [520 x 1024] = seq[520 x 256] @ w_ih0^T + biases ----
        float* As = smem;          // [16][68]
        float* Bs = smem + 1088;
        const int bm = (blk % 9) * 64, bn = (blk / 9) * 64;
        float acc[4][4] = {};
        for (int k0 = 0; k0 < 256; k0 += 16) {
            {
                int m = bm + arow;
                float4 v = make_float4(0.f, 0.f, 0.f, 0.f);
                if (m < 520) {
                    int s = m % 65, b = m / 65;
                    const float* src = (s == 0) ? (init_i + k0 + akq)
                        : (lstm_in + ((size_t)b * TT + (s - 1)) * DD + k0 + akq);
                    v = *(const float4*)src;
                }
                As[(akq + 0) * 68 + arow] = v.x; As[(akq + 1) * 68 + arow] = v.y;
                As[(akq + 2) * 68 + arow] = v.z; As[(akq + 3) * 68 + arow] = v.w;
            }
            {
                int n = bn + arow;
                float4 v = *(const float4*)(w_ih + (size_t)n * 256 + k0 + akq);
                Bs[(akq + 0) * 68 + (n - bn)] = v.x; Bs[(akq + 1) * 68 + (n - bn)] = v.y;
                Bs[(akq + 2) * 68 + (n - bn)] = v.z; Bs[(akq + 3) * 68 + (n - bn)] = v.w;
            }
            __syncthreads();
#pragma unroll
            for (int kk = 0; kk < 16; ++kk) {
                float4 a = *(const float4*)&As[kk * 68 + tm];
                float4 b = *(const float4*)&Bs[kk * 68 + tn];
                float av[4] = {a.x, a.y, a.z, a.w};
                float bv[4] = {b.x, b.y, b.z, b.w};
#pragma unroll
                for (int i = 0; i < 4; ++i)
#pragma unroll
                    for (int jj = 0; jj < 4; ++jj)
                        acc[i][jj] = fmaf(av[i], bv[jj], acc[i][jj]);
            }
            __syncthreads();
        }
        float bad[4];
#pragma unroll
        for (int jj = 0; jj < 4; ++jj)
            bad[jj] = b_ih[bn + tn + jj] + b_hh[bn + tn + jj];
#pragma unroll
        for (int i = 0; i < 4; ++i) {
            int m = bm + tm + i;
            if (m < 520)
                *(float4*)(xg0 + (size_t)m * 1024 + bn + tn) =
                    make_float4(acc[i][0] + bad[0], acc[i][1] + bad[1],
                                acc[i][2] + bad[2], acc[i][3] + bad[3]);
        }
    } else {
        // ---- dual-feat GEMM: 64x64 tile of attn_feat & hop_feat ----
        float* As  = smem;
        float* Bs  = smem + 1088;
        float* Bs2 = smem + 2176;
        const int tileid = blk - 144;                 // 0..255
        const int bm = (tileid & 63) * 64, bn = (tileid >> 6) * 64;
        float acc1[4][4] = {}, acc2[4][4] = {};
        for (int k0 = 0; k0 < 256; k0 += 16) {
            float4 va = *(const float4*)(attn_mem + (size_t)(bm + arow) * 256 + k0 + akq);
            As[(akq + 0) * 68 + arow] = va.x; As[(akq + 1) * 68 + arow] = va.y;
            As[(akq + 2) * 68 + arow] = va.z; As[(akq + 3) * 68 + arow] = va.w;
            int kk = tid >> 4, nq = (tid & 15) << 2;
            *(float4*)&Bs[kk * 68 + nq]  = *(const float4*)(attn_wm + (size_t)(k0 + kk) * 256 + bn + nq);
            *(float4*)&Bs2[kk * 68 + nq] = *(const float4*)(hop_wm  + (size_t)(k0 + kk) * 256 + bn + nq);
            __syncthreads();
#pragma unroll
            for (int kk2 = 0; kk2 < 16; ++kk2) {
                float4 a  = *(const float4*)&As[kk2 * 68 + tm];
                float4 b1 = *(const float4*)&Bs[kk2 * 68 + tn];
                float4 b2 = *(const float4*)&Bs2[kk2 * 68 + tn];
                float av[4] = {a.x, a.y, a.z, a.w};
                float b1v[4] = {b1.x, b1.y, b1.z, b1.w};
                float b2v[4] = {b2.x, b2.y, b2.z, b2.w};
#pragma unroll
                for (int i = 0; i < 4; ++i)
#pragma unroll
                    for (int jj = 0; jj < 4; ++jj) {
                        acc1[i][jj] = fmaf(av[i], b1v[jj], acc1[i][jj]);
                        acc2[i][jj] = fmaf(av[i], b2v[jj], acc2[i][jj]);
                    }
            }
            __syncthreads();
        }
#pragma unroll
        for (int i = 0; i < 4; ++i) {
            int m = bm + tm + i;
            *(float4*)(attn_feat + (size_t)m * 256 + bn + tn) =
                make_float4(acc1[i][0], acc1[i][1], acc1[i][2], acc1[i][3]);
            *(float4*)(hop_feat + (size_t)m * 256 + bn + tn) =
                make_float4(acc2[i][0], acc2[i][1], acc2[i][2], acc2[i][3]);
        }
    }
}

// ---------------------------------------------------------------------------
// persistent 2-layer LSTM, data-as-flag sync, weights in LDS.
// 96 blocks x 1024 threads. b in low tid bits -> weight ds_reads are
// 8-distinct x 8-broadcast (conflict-free); rows padded to 260 floats.
// ---------------------------------------------------------------------------
__device__ __forceinline__ float dot16(const float4* __restrict__ w,
                                       const float4* __restrict__ hp) {
    float4 s = make_float4(0.f, 0.f, 0.f, 0.f);
#pragma unroll
    for (int k = 0; k < 16; ++k) {
        float4 w4 = w[k];
        float4 h4 = hp[k];
        s.x = fmaf(w4.x, h4.x, s.x);
        s.y = fmaf(w4.y, h4.y, s.y);
        s.z = fmaf(w4.z, h4.z, s.z);
        s.w = fmaf(w4.w, h4.w, s.w);
    }
    return (s.x + s.y) + (s.z + s.w);
}

__device__ __forceinline__ void poll2(const unsigned long long* p, unsigned want,
                                      float* d0, float* d1) {
    unsigned long long a = __hip_atomic_load(p,     __ATOMIC_RELAXED, __HIP_MEMORY_SCOPE_AGENT);
    unsigned long long b = __hip_atomic_load(p + 1, __ATOMIC_RELAXED, __HIP_MEMORY_SCOPE_AGENT);
    while ((unsigned)(a >> 32) != want)
        a = __hip_atomic_load(p, __ATOMIC_RELAXED, __HIP_MEMORY_SCOPE_AGENT);
    while ((unsigned)(b >> 32) != want)
        b = __hip_atomic_load(p + 1, __ATOMIC_RELAXED, __HIP_MEMORY_SCOPE_AGENT);
    *d0 = __uint_as_float((unsigned)a);
    *d1 = __uint_as_float((unsigned)b);
}

__global__ void __launch_bounds__(1024) lstm_kernel(
    const float* __restrict__ w_ih, const float* __restrict__ w_hh,
    const float* __restrict__ b_ih, const float* __restrict__ b_hh,
    const float* __restrict__ xg0, const float* __restrict__ init_c,
    unsigned long long* __restrict__ S0, unsigned long long* __restrict__ S1,
    float* __restrict__ query)
{
    __shared__ __align__(16) float wlds[32 * 260];   // 33.3 KB
    __shared__ __align__(16) float hls[2 * 8 * 260]; // 16.6 KB
    __shared__ float part[1024];
    const int tid = threadIdx.x;
    const int blk = blockIdx.x;
    const bool is1 = blk >= 32;
    const int j0 = is1 ? (blk - 32) * 4 : blk * 8;

    // ---- stage this block's weight slice (32 KB) to LDS ----
    if (!is1) {
        for (int idx = tid; idx < 8192; idx += 1024) {
            int r = idx >> 8, h = idx & 255;             // r = gate*8 + jl
            int gate = r >> 3, jl = r & 7;
            wlds[r * 260 + h] = w_hh[((size_t)(gate * HH + j0 + jl)) * HH + h];
        }
    } else {
        for (int idx = tid; idx < 8192; idx += 1024) {
            int r = idx >> 8, h = idx & 255;             // r = half*16 + gate*4 + jl
            int half = r >> 4, gate = (r >> 2) & 3, jl = r & 3;
            const float* src = half ? w_hh : w_ih;
            wlds[r * 260 + h] = src[((size_t)(G4 + gate * HH + j0 + jl)) * HH + h];
        }
    }
    // staging map: thread stages payload pair (2tid, 2tid+1) of a 2048-slot set
    const int g = tid * 2;
    const int bs = g >> 8, hs = g & 255;
    const int fj = is1 ? (tid >> 3) : (tid >> 3);        // finisher j (tid small)
    const int fb = tid & 7;

    if (!is1) {
        // ------------------------ layer 0 ------------------------
        const int b = tid & 7, jl = (tid >> 3) & 7, gate = (tid >> 5) & 3, seg = tid >> 8;
        const float4* wp = (const float4*)&wlds[(gate * 8 + jl) * 260 + seg * 64];
        const int pidx = seg * 256 + gate * 64 + jl * 8 + b;
        float* const dst = &hls[bs * 260 + hs];
        const float4* hp = (const float4*)&hls[b * 260 + seg * 64];
        float creg = (tid < 64) ? init_c[j0 + fj] : 0.f;

        for (int t = 0; t < SS; ++t) {
            float xg[4];
            if (tid < 64) {
                const float* xp = xg0 + ((size_t)fb * SS + t) * G4 + (j0 + fj);
#pragma unroll
                for (int gg = 0; gg < 4; ++gg) xg[gg] = xp[gg * 256];
            }
            poll2(S0 + (size_t)t * 2048 + g, (unsigned)(t + 1), dst, dst + 1);
            __syncthreads();                 // (also covers weight staging at t=0)
            part[pidx] = dot16(wp, hp);
            __syncthreads();
            if (tid < 64) {
                float g0 = xg[0], g1 = xg[1], g2 = xg[2], g3 = xg[3];
#pragma unroll
                for (int s2 = 0; s2 < 4; ++s2) {
                    const float* pp = &part[s2 * 256 + fj * 8 + fb];
                    g0 += pp[0];  g1 += pp[64]; g2 += pp[128]; g3 += pp[192];
                }
                float c = fsigmoid(g1) * creg + fsigmoid(g0) * ftanh(g2);
                float h = fsigmoid(g3) * ftanh(c);
                creg = c;
                unsigned long long u = ((unsigned long long)(unsigned)(t + 2) << 32)
                                     | (unsigned long long)(unsigned)__float_as_uint(h);
                __hip_atomic_store(S0 + (size_t)(t + 1) * 2048 + fb * 256 + (j0 + fj), u,
                                   __ATOMIC_RELAXED, __HIP_MEMORY_SCOPE_AGENT);
            }
        }
    } else {
        // ------------------------ layer 1 ------------------------
        const int b = tid & 7, jl = (tid >> 3) & 3, gate = (tid >> 5) & 3;
        const int half = (tid >> 7) & 1, seg = tid >> 8;
        const float4* wp = (const float4*)&wlds[(half * 16 + gate * 4 + jl) * 260 + seg * 64];
        const int pidx = seg * 256 + half * 128 + gate * 32 + jl * 8 + b;
        float* const dst0 = &hls[bs * 260 + hs];
        float* const dst1 = &hls[2080 + bs * 260 + hs];
        const float4* hp = (const float4*)&hls[half * 2080 + b * 260 + seg * 64];
        float creg = 0.f, bias[4] = {0.f, 0.f, 0.f, 0.f};
        if (tid < 32) {
            creg = init_c[HH + j0 + fj];
#pragma unroll
            for (int gg = 0; gg < 4; ++gg)
                bias[gg] = b_ih[G4 + gg * HH + j0 + fj] + b_hh[G4 + gg * HH + j0 + fj];
        }

        for (int t = 0; t < SS; ++t) {
            poll2(S0 + (size_t)(t + 1) * 2048 + g, (unsigned)(t + 2), dst0, dst0 + 1);
            __syncthreads();
            if (half == 0) part[pidx] = dot16(wp, hp);
            poll2(S1 + (size_t)t * 2048 + g, (unsigned)(t + 1), dst1, dst1 + 1);
            __syncthreads();
            if (half == 1) part[pidx] = dot16(wp, hp);
            __syncthreads();
            if (tid < 32) {
                float g0 = bias[0], g1 = bias[1], g2 = bias[2], g3 = bias[3];
#pragma unroll
                for (int s2 = 0; s2 < 8; ++s2) {   // s2 = seg*2 + half
                    const float* pp = &part[(s2 >> 1) * 256 + (s2 & 1) * 128 + fj * 8 + fb];
                    g0 += pp[0]; g1 += pp[32]; g2 += pp[64]; g3 += pp[96];
                }
                float c = fsigmoid(g1) * creg + fsigmoid(g0) * ftanh(g2);
                float h = fsigmoid(g3) * ftanh(c);
                creg = c;
                int jj = j0 + fj;
                unsigned long long u = ((unsigned long long)(unsigned)(t + 2) << 32)
                                     | (unsigned long long)(unsigned)__float_as_uint(h);
                __hip_atomic_store(S1 + (size_t)(t + 1) * 2048 + fb * 256 + jj, u,
                                   __ATOMIC_RELAXED, __HIP_MEMORY_SCOPE_AGENT);
                query[((size_t)fb * SS + t) * HH + jj] = h;
            }
        }
    }
}

// ---------------------------------------------------------------------------
// small fp32 GEMM (64x64 tile), C = A[M,K] @ B[K,N]   (q1 / q2)
// ---------------------------------------------------------------------------
__global__ void __launch_bounds__(256) gemm_kernel(
    const float* __restrict__ A, const float* __restrict__ B,
    float* __restrict__ C, int M, int N, int K)
{
    __shared__ __align__(16) float As[16 * 68];
    __shared__ __align__(16) float Bs[16 * 68];
    const int tid = threadIdx.x;
    const int bm = blockIdx.x * 64, bn = blockIdx.y * 64;
    const int tm = (tid >> 4) * 4, tn = (tid & 15) * 4;
    const int arow = tid >> 2, akq = (tid & 3) << 2;
    float acc[4][4] = {};
    for (int k0 = 0; k0 < K; k0 += 16) {
        {
            int m = bm + arow;
            float4 v = make_float4(0.f, 0.f, 0.f, 0.f);
            if (m < M) v = *(const float4*)(A + (size_t)m * K + k0 + akq);
            As[(akq + 0) * 68 + arow] = v.x; As[(akq + 1) * 68 + arow] = v.y;
            As[(akq + 2) * 68 + arow] = v.z; As[(akq + 3) * 68 + arow] = v.w;
        }
        {
            int kk = tid >> 4, nq = (tid & 15) << 2;
            *(float4*)&Bs[kk * 68 + nq] = *(const float4*)(B + (size_t)(k0 + kk) * N + bn + nq);
        }
        __syncthreads();
#pragma unroll
        for (int kk2 = 0; kk2 < 16; ++kk2) {
            float4 a = *(const float4*)&As[kk2 * 68 + tm];
            float4 b = *(const float4*)&Bs[kk2 * 68 + tn];
            float av[4] = {a.x, a.y, a.z, a.w};
            float bv[4] = {b.x, b.y, b.z, b.w};
#pragma unroll
            for (int i = 0; i < 4; ++i)
#pragma unroll
                for (int jj = 0; jj < 4; ++jj)
                    acc[i][jj] = fmaf(av[i], bv[jj], acc[i][jj]);
        }
        __syncthreads();
    }
#pragma unroll
    for (int i = 0; i < 4; ++i) {
        int m = bm + tm + i;
        if (m < M)
            *(float4*)(C + (size_t)m * N + bn + tn) =
                make_float4(acc[i][0], acc[i][1], acc[i][2], acc[i][3]);
    }
}

// ---------------------------------------------------------------------------
// additive score, s-tiled + exp-factorized:
//   out[b,s,n] = Vsum - 2 * sum_h v[h] / (e^{2 feat[b,n,h]} * e^{2 q[b,s,h]} + 1)
// block = (n-tile 64, s-tile 13, b); each thread owns one (n,s) pair.
// ---------------------------------------------------------------------------
__global__ void __launch_bounds__(256) score2_kernel(
    const float* __restrict__ feat, const float* __restrict__ qv,
    const float* __restrict__ v, const int* __restrict__ mem_sizes,
    float* __restrict__ outp, int masked)
{
    const int nt = blockIdx.x, st = blockIdx.y, b = blockIdx.z;
    const int tid = threadIdx.x;
    const int n0 = nt * 64, s0 = st * 13;
    const int msize = masked ? mem_sizes[b] : NN;
    if (n0 >= msize) return;
    __shared__ float efls[32 * 261];
    __shared__ float eqls[13 * 261];
    __shared__ float vls[256];

    vls[tid] = v[tid];
    for (int k = 0; k < 13; ++k)
        eqls[k * 261 + tid] = __expf(2.f * qv[((size_t)b * SS + s0 + k) * HH + tid]);
    __syncthreads();
    float vsum = 0.f;
    {
        float p0 = 0.f, p1 = 0.f, p2 = 0.f, p3 = 0.f;
#pragma unroll
        for (int h = 0; h < 256; h += 4) {
            p0 += vls[h]; p1 += vls[h + 1]; p2 += vls[h + 2]; p3 += vls[h + 3];
        }
        vsum = (p0 + p1) + (p2 + p3);
    }

    for (int c = 0; c < 2; ++c) {
        const int nbase = n0 + c * 32;
        int nrows = msize - nbase; nrows = nrows < 0 ? 0 : (nrows > 32 ? 32 : nrows);
        __syncthreads();
        for (int k = 0; k < nrows; ++k)
            efls[k * 261 + tid] = __expf(2.f * feat[((size_t)b * NN + nbase + k) * HH + tid]);
        __syncthreads();
#pragma unroll
        for (int i = 0; i < 2; ++i) {
            int p = i * 256 + tid;
            if (p < 416) {
                int s = p >> 5, nl = p & 31;
                if (nl < nrows) {
                    const float* ef = &efls[nl * 261];
                    const float* eq = &eqls[s * 261];
                    float acc = 0.f;
#pragma unroll 4
                    for (int h = 0; h < 256; ++h)
                        acc = fmaf(vls[h],
                                   __builtin_amdgcn_rcpf(fmaf(ef[h], eq[h], 1.f)),
                                   acc);
                    outp[((size_t)b * SS + s0 + s) * NN + (nbase + nl)] =
                        fmaf(-2.f, acc, vsum);
                }
            }
        }
    }
}

// ---------------------------------------------------------------------------
// fused softmax + weighted sum per (b, s-tile of 13):
//   p = softmax_n(sc[b,s,:msize]);  q2raw[b,s,h] = sum_n p[n] * feat[b,n,h]
// ---------------------------------------------------------------------------
__global__ void __launch_bounds__(256) smwsum_kernel(
    const float* __restrict__ sc, const float* __restrict__ feat,
    const int* __restrict__ mem_sizes, float* __restrict__ q2raw)
{
    const int st = blockIdx.x, b = blockIdx.y;
    const int tid = threadIdx.x;
    const int s0 = st * 13;
    const int msize = mem_sizes[b];
    __shared__ float pls[13 * 520];
    for (int i = tid; i < 13 * 512; i += 256) {
        int s = i >> 9, n = i & 511;
        pls[s * 520 + n] = (n < msize)
            ? sc[((size_t)b * SS + s0 + s) * NN + n] : -3e38f;
    }
    __syncthreads();
    const int lane = tid & 63, wv = tid >> 6;
    for (int r = wv; r < 13; r += 4) {
        float x[8];
        float m = -3e38f;
#pragma unroll
        for (int k = 0; k < 8; ++k) {
            x[k] = pls[r * 520 + lane + 64 * k];
            m = fmaxf(m, x[k]);
        }
#pragma unroll
        for (int off = 32; off; off >>= 1) m = fmaxf(m, __shfl_xor(m, off, 64));
        float l = 0.f;
#pragma unroll
        for (int k = 0; k < 8; ++k) { x[k] = __expf(x[k] - m); l += x[k]; }
#pragma unroll
        for (int off = 32; off; off >>= 1) l += __shfl_xor(l, off, 64);
        float inv = __builtin_amdgcn_rcpf(l);
#pragma unroll
        for (int k = 0; k < 8; ++k) pls[r * 520 + lane + 64 * k] = x[k] * inv;
    }
    __syncthreads();
    float acc[13];
#pragma unroll
    for (int s = 0; s < 13; ++s) acc[s] = 0.f;
    const float* fb = feat + (size_t)b * NN * HH + tid;
    int n = 0;
    for (; n + 2 <= msize; n += 2) {
        float f0 = fb[(size_t)n * HH];
        float f1 = fb[(size_t)(n + 1) * HH];
#pragma unroll
        for (int s = 0; s < 13; ++s) {
            acc[s] = fmaf(pls[s * 520 + n], f0, acc[s]);
            acc[s] = fmaf(pls[s * 520 + n + 1], f1, acc[s]);
        }
    }
    if (n < msize) {
        float f0 = fb[(size_t)n * HH];
#pragma unroll
        for (int s = 0; s < 13; ++s) acc[s] = fmaf(pls[s * 520 + n], f0, acc[s]);
    }
#pragma unroll
    for (int s = 0; s < 13; ++s)
        q2raw[((size_t)b * SS + s0 + s) * HH + tid] = acc[s];
}

// ---------------------------------------------------------------------------
extern "C" void kernel_launch(void* const* d_in, const int* in_sizes, int n_in,
                              void* d_out, int out_size, void* d_ws, size_t ws_size,
                              hipStream_t stream) {
    const float* attn_mem  = (const float*)d_in[0];
    const int*   mem_sizes = (const int*)d_in[1];
    const float* lstm_in   = (const float*)d_in[2];
    const float* init_h    = (const float*)d_in[3];
    const float* init_c    = (const float*)d_in[4];
    const float* init_i    = (const float*)d_in[5];
    const float* w_ih      = (const float*)d_in[6];
    const float* w_hh      = (const float*)d_in[7];
    const float* b_ih      = (const float*)d_in[8];
    const float* b_hh      = (const float*)d_in[9];
    const float* attn_wm   = (const float*)d_in[10];
    const float* attn_wq   = (const float*)d_in[11];
    const float* attn_v    = (const float*)d_in[12];
    const float* hop_wm    = (const float*)d_in[13];
    const float* hop_wq    = (const float*)d_in[14];
    const float* hop_v     = (const float*)d_in[15];
    float* out = (float*)d_out;

    float* ws        = (float*)d_ws;
    float* attn_feat = ws;                 // 1,048,576 floats
    float* hop_feat  = ws + 1048576;       // 1,048,576
    float* xg0       = ws + 2097152;       //   532,480
    float* query     = ws + 2629632;       //   133,120
    // overlaid region (lstm phase vs post phase)
    float* region    = ws + 2762752;
    unsigned long long* S0 = (unsigned long long*)region;            // 135,168 u64
    unsigned long long* S1 = (unsigned long long*)(region + 270336); // 135,168 u64
    float* q1     = region;                // 133,120 (S dead by then)
    float* sc     = region + 133120;       // 266,240
    float* q2raw  = region + 399360;       // 133,120
    float* q2     = region + 532480;       // 133,120

    pre_kernel<<<1456, 256, 0, stream>>>(lstm_in, init_i, init_h, w_ih, b_ih, b_hh,
                                         xg0, attn_mem, attn_wm, hop_wm,
                                         attn_feat, hop_feat, S0, S1);
    {
        void* args[] = { (void*)&w_ih, (void*)&w_hh, (void*)&b_ih, (void*)&b_hh,
                         (void*)&xg0, (void*)&init_c, (void*)&S0, (void*)&S1,
                         (void*)&query };
        hipLaunchCooperativeKernel(lstm_kernel, dim3(96), dim3(1024), args, 0u, stream);
    }
    gemm_kernel<<<dim3(9, 4), 256, 0, stream>>>(query, hop_wq, q1, 520, 256, 256);
    score2_kernel<<<dim3(8, 5, 8), 256, 0, stream>>>(hop_feat, q1, hop_v,
                                                     mem_sizes, sc, 1);
    smwsum_kernel<<<dim3(5, 8), 256, 0, stream>>>(sc, hop_feat, mem_sizes, q2raw);
    gemm_kernel<<<dim3(9, 4), 256, 0, stream>>>(q2raw, attn_wq, q2, 520, 256, 256);
    score2_kernel<<<dim3(8, 5, 8), 256, 0, stream>>>(attn_feat, q2, attn_v,
                                                     mem_sizes, out, 0);
}